// Round 9
// baseline (36.172 us; speedup 1.0000x reference)
//
#include <hip/hip_runtime.h>

// RandomResizedCropPair: bilinear crop-resize (image) + nearest crop-resize (mask)
// image: [32,3,512,512] f32, mask: [32,1,512,512] f32
// out: img [32,3,384,384] f32 ++ msk [32,1,384,384] f32
//
// R8: R7's 4-rows/block LDS staging, but thread = (row, 4-column group):
// stores become f32x4 NT (16 scalar -> 4 vector per thread), mask gathers
// 4 -> 1 row. VMEM/thread 26 -> 14. Staging identical to R7.

constexpr int OUT = 384;
constexpr int H = 512;
constexpr int W = 512;
constexpr int B = 32;
constexpr int C = 3;
constexpr int RPB = 4;                 // output rows per block
constexpr int GPB = OUT / RPB;         // 96 row-groups per image
constexpr int NBLK = B * GPB;          // 3072
constexpr int BPX  = NBLK / 8;         // 384 blocks/XCD = 4 whole images
constexpr int NSLOT = 6;               // input-row slots per channel
constexpr int LROWS = C * NSLOT;       // 18
constexpr int LDSW  = 520;             // dword row stride (512 data + guard + pad)
constexpr int JQ    = OUT / 4;         // 96 column groups per row

typedef float f32x4 __attribute__((ext_vector_type(4)));

__global__ __launch_bounds__(OUT) void rrc_pair_kernel(
    const float* __restrict__ image,
    const float* __restrict__ mask,
    const int* __restrict__ crop_size,
    const int* __restrict__ top,
    const int* __restrict__ left,
    float* __restrict__ img_out,
    float* __restrict__ msk_out)
{
    __shared__ float lds[LROWS * LDSW];

    // Bijective XCD swizzle: hw%8 = XCD, each XCD owns 4 whole images.
    const int hw = blockIdx.x;
    const int logical = (hw & 7) * BPX + (hw >> 3);
    const int b  = logical / GPB;                 // block-uniform
    const int i0 = (logical % GPB) * RPB;         // first output row
    const int tid = (int)threadIdx.x;

    const int cs = crop_size[b];
    const int t  = top[b];
    const int l  = left[b];
    const float csf = (float)cs;
    const float s   = csf / (float)OUT;           // match reference order

    // Block-uniform base input row (iy0 of the group's first output row).
    float cy0 = ((float)i0 + 0.5f) * s - 0.5f;
    cy0 = fminf(fmaxf(cy0, 0.0f), csf - 1.0f);
    const int base_y = (int)floorf(cy0);

    const float* imgb = image + (size_t)b * C * H * W;

    // --- stage 18 input rows (full 512 width) + guard word per row ---
    // 18*512 = 9216 floats = 2304 f32x4 chunks = 384 threads x 6.
    #pragma unroll
    for (int k = 0; k < 6; ++k) {
        const int q   = tid + k * OUT;            // chunk id 0..2303
        const int r   = q >> 7;                   // LDS row 0..17
        const int col = (q & 127) * 4;
        const int c    = r / NSLOT;
        const int slot = r % NSLOT;
        const int y = min(t + base_y + slot, H - 1);
        const float* src = imgb + ((size_t)c * H + (size_t)y) * W + col;
        f32x4 v = *(const f32x4*)src;
        *(f32x4*)&lds[r * LDSW + col] = v;
        if ((q & 127) == 127) lds[r * LDSW + 512] = v[3];  // guard = copy of col 511
    }

    // --- this thread's pixels: row i0+r4, columns 4*jq .. 4*jq+3 ---
    const int r4 = tid / JQ;                      // 0..3
    const int jq = tid - r4 * JQ;                 // 0..95
    const int i  = i0 + r4;

    // y geometry (one row per thread now)
    float cy = ((float)i + 0.5f) * s - 0.5f;
    cy = fminf(fmaxf(cy, 0.0f), csf - 1.0f);
    int   iy0 = (int)floorf(cy);
    int   iy1 = min(iy0 + 1, cs - 1);
    float wy  = cy - (float)iy0;
    const int slot0 = iy0 - base_y;               // 0..4
    const int slot1 = min(iy1 - base_y, NSLOT - 1);

    // x geometry for 4 consecutive columns
    int   x0a[4];
    float wxa[4];
    #pragma unroll
    for (int k = 0; k < 4; ++k) {
        const int j = jq * 4 + k;
        float cx = ((float)j + 0.5f) * s - 0.5f;
        cx = fminf(fmaxf(cx, 0.0f), csf - 1.0f);
        int ix0 = (int)floorf(cx);
        wxa[k] = cx - (float)ix0;
        x0a[k] = ix0 + l;                         // read cols x0, x0+1 (guarded)
    }

    // --- mask gathers before the barrier (overlap staging latency) ---
    int my = min((i * cs) / OUT, cs - 1);
    const float* mrow = mask + ((size_t)b * H + (size_t)(my + t)) * W;
    f32x4 mv;
    #pragma unroll
    for (int k = 0; k < 4; ++k) {
        const int j = jq * 4 + k;
        int mx = min((j * cs) / OUT, cs - 1);
        mv[k] = mrow[mx + l];
    }

    __syncthreads();

    const size_t o_row = (size_t)b * C * OUT * OUT + (size_t)i * OUT + (size_t)jq * 4;

    #pragma unroll
    for (int c = 0; c < C; ++c) {
        const float* rA = &lds[(c * NSLOT + slot0) * LDSW];
        const float* rB = &lds[(c * NSLOT + slot1) * LDSW];
        f32x4 o;
        #pragma unroll
        for (int k = 0; k < 4; ++k) {
            const float wx = wxa[k];
            const int   x0 = x0a[k];
            float v00 = rA[x0], v01 = rA[x0 + 1];   // ds_read2_b32
            float v10 = rB[x0], v11 = rB[x0 + 1];
            float topv = v00 + (v01 - v00) * 0.0f;  // placeholder removed below
            (void)topv;
            o[k] = (v00 * (1.0f - wx) + v01 * wx) * (1.0f - wy)
                 + (v10 * (1.0f - wx) + v11 * wx) * wy;
        }
        __builtin_nontemporal_store(o, (f32x4*)(img_out + o_row + (size_t)c * OUT * OUT));
    }

    __builtin_nontemporal_store(mv,
        (f32x4*)(msk_out + (size_t)b * OUT * OUT + (size_t)i * OUT + (size_t)jq * 4));
}

extern "C" void kernel_launch(void* const* d_in, const int* in_sizes, int n_in,
                              void* d_out, int out_size, void* d_ws, size_t ws_size,
                              hipStream_t stream) {
    const float* image = (const float*)d_in[0];
    const float* mask  = (const float*)d_in[1];
    const int* cs      = (const int*)d_in[2];
    const int* top     = (const int*)d_in[3];
    const int* left    = (const int*)d_in[4];

    float* img_out = (float*)d_out;
    float* msk_out = img_out + (size_t)B * C * OUT * OUT;

    dim3 block(OUT);
    dim3 grid(NBLK);
    hipLaunchKernelGGL(rrc_pair_kernel, grid, block, 0, stream,
                       image, mask, cs, top, left, img_out, msk_out);
}

// Round 10
// 34.925 us; speedup vs baseline: 1.0357x; 1.0357x over previous
//
#include <hip/hip_runtime.h>

// RandomResizedCropPair: bilinear crop-resize (image) + nearest crop-resize (mask)
// image: [32,3,512,512] f32, mask: [32,1,512,512] f32
// out: img [32,3,384,384] f32 ++ msk [32,1,384,384] f32
//
// R9: persistent double-buffered pipeline. 512 blocks (2/CU exactly), each
// owns 6 consecutive 4-row groups of one image. Per group: issue next
// group's staging loads (regs) -> compute current group from LDS (R7's
// thread=column layout, lane stride ~1 => low bank conflict) -> write regs
// to the other LDS buffer -> barrier. HBM latency hides under compute.
// XCD swizzle (64 blocks/XCD = 2 images) + NT stores kept.

constexpr int OUT = 384;
constexpr int H = 512;
constexpr int W = 512;
constexpr int B = 32;
constexpr int C = 3;
constexpr int RPB = 4;                     // output rows per group
constexpr int GPB = OUT / RPB;             // 96 groups per image
constexpr int GRP_PER_BLK = 6;
constexpr int BLK_PER_IMG = GPB / GRP_PER_BLK;   // 16
constexpr int NBLK = B * BLK_PER_IMG;      // 512 = 2 per CU
constexpr int BPX  = NBLK / 8;             // 64 blocks/XCD = 2 whole images
constexpr int NSLOT = 6;                   // input-row slots per channel
constexpr int LROWS = C * NSLOT;           // 18
constexpr int BUFSZ = LROWS * W;           // 9216 dwords per buffer (linear rows)

typedef float f32x4 __attribute__((ext_vector_type(4)));

__global__ __launch_bounds__(OUT, 3) void rrc_pair_kernel(
    const float* __restrict__ image,
    const float* __restrict__ mask,
    const int* __restrict__ crop_size,
    const int* __restrict__ top,
    const int* __restrict__ left,
    float* __restrict__ img_out,
    float* __restrict__ msk_out)
{
    __shared__ float lds[2 * BUFSZ + 8];   // two buffers + zeroed guard words

    const int hw = blockIdx.x;
    const int logical = (hw & 7) * BPX + (hw >> 3);
    const int b  = logical / BLK_PER_IMG;              // block-uniform
    const int g0 = (logical % BLK_PER_IMG) * GRP_PER_BLK;  // first group
    const int tid = (int)threadIdx.x;                  // = output column j

    const int cs = crop_size[b];
    const int t  = top[b];
    const int l  = left[b];
    const float csf = (float)cs;
    const float s   = csf / (float)OUT;                // match reference order

    const float* imgb = image + (size_t)b * C * H * W;
    const float* mskb = mask + (size_t)b * H * W;

    // --- per-thread chunk geometry (constant across groups) ---
    // chunk k: q = tid + k*384 in [0,2304); LDS row r=q>>7, col=(q&127)*4
    int ck[6], slotk[6], colk[6], qd[6];
    #pragma unroll
    for (int k = 0; k < 6; ++k) {
        const int q = tid + k * OUT;
        const int r = q >> 7;
        colk[k]  = (q & 127) * 4;
        ck[k]    = r / NSLOT;
        slotk[k] = r % NSLOT;
        qd[k]    = q * 4;          // dword offset within buffer
    }

    // --- x geometry once per thread ---
    float cx = ((float)tid + 0.5f) * s - 0.5f;
    cx = fminf(fmaxf(cx, 0.0f), csf - 1.0f);
    const int   ix0 = (int)floorf(cx);
    const float wx  = cx - (float)ix0;
    const int   x0  = ix0 + l;                // read x0, x0+1 (overread safe)
    const int   mx  = min((tid * cs) / OUT, cs - 1) + l;

    // base input row for a group
    auto base_y_of = [&](int grp) -> int {
        float cy0 = ((float)(grp * RPB) + 0.5f) * s - 0.5f;
        cy0 = fminf(fmaxf(cy0, 0.0f), csf - 1.0f);
        return (int)floorf(cy0);
    };

    // --- prologue: stage group g0 into buffer 0 ---
    int cur_base_y = base_y_of(g0);
    {
        f32x4 v[6];
        #pragma unroll
        for (int k = 0; k < 6; ++k) {
            const int y = min(t + cur_base_y + slotk[k], H - 1);
            v[k] = *(const f32x4*)(imgb + ((size_t)ck[k] * H + (size_t)y) * W + colk[k]);
        }
        if (tid < 8) lds[2 * BUFSZ + tid] = 0.0f;
        #pragma unroll
        for (int k = 0; k < 6; ++k)
            *(f32x4*)&lds[qd[k]] = v[k];
    }
    __syncthreads();

    for (int gg = 0; gg < GRP_PER_BLK; ++gg) {
        const int cur = gg & 1;
        const int i0 = (g0 + gg) * RPB;

        // issue next group's staging loads first (latency overlaps compute)
        f32x4 nv[6];
        int nbase_y = cur_base_y;
        if (gg + 1 < GRP_PER_BLK) {
            nbase_y = base_y_of(g0 + gg + 1);
            #pragma unroll
            for (int k = 0; k < 6; ++k) {
                const int y = min(t + nbase_y + slotk[k], H - 1);
                nv[k] = *(const f32x4*)(imgb + ((size_t)ck[k] * H + (size_t)y) * W + colk[k]);
            }
        }

        // mask gathers for this group's 4 rows
        float mval[RPB];
        #pragma unroll
        for (int r4 = 0; r4 < RPB; ++r4) {
            int my = min(((i0 + r4) * cs) / OUT, cs - 1);
            mval[r4] = mskb[(size_t)(my + t) * W + mx];
        }

        // compute from buf[cur]
        const float* buf = &lds[cur * BUFSZ];
        #pragma unroll
        for (int r4 = 0; r4 < RPB; ++r4) {
            const int i = i0 + r4;
            float cy = ((float)i + 0.5f) * s - 0.5f;
            cy = fminf(fmaxf(cy, 0.0f), csf - 1.0f);
            int   iy0 = (int)floorf(cy);
            int   iy1 = min(iy0 + 1, cs - 1);
            float wy  = cy - (float)iy0;
            const int slot0 = iy0 - cur_base_y;
            const int slot1 = min(iy1 - cur_base_y, NSLOT - 1);

            const float w00 = (1.0f - wy) * (1.0f - wx);
            const float w01 = (1.0f - wy) * wx;
            const float w10 = wy * (1.0f - wx);
            const float w11 = wy * wx;

            const size_t o_base = (size_t)b * C * OUT * OUT + (size_t)i * OUT + (size_t)tid;

            #pragma unroll
            for (int c = 0; c < C; ++c) {
                const float* rA = &buf[(c * NSLOT + slot0) * W];
                const float* rB = &buf[(c * NSLOT + slot1) * W];
                float v00 = rA[x0], v01 = rA[x0 + 1];   // ds_read2_b32
                float v10 = rB[x0], v11 = rB[x0 + 1];
                float rr = v00 * w00 + v01 * w01 + v10 * w10 + v11 * w11;
                __builtin_nontemporal_store(rr, img_out + o_base + (size_t)c * OUT * OUT);
            }
            __builtin_nontemporal_store(mval[r4],
                msk_out + (size_t)b * OUT * OUT + (size_t)i * OUT + (size_t)tid);
        }

        // write next group's rows into the other buffer
        if (gg + 1 < GRP_PER_BLK) {
            float* nbuf = &lds[(cur ^ 1) * BUFSZ];
            #pragma unroll
            for (int k = 0; k < 6; ++k)
                *(f32x4*)&nbuf[qd[k]] = nv[k];
            cur_base_y = nbase_y;
        }
        __syncthreads();
    }
}

extern "C" void kernel_launch(void* const* d_in, const int* in_sizes, int n_in,
                              void* d_out, int out_size, void* d_ws, size_t ws_size,
                              hipStream_t stream) {
    const float* image = (const float*)d_in[0];
    const float* mask  = (const float*)d_in[1];
    const int* cs      = (const int*)d_in[2];
    const int* top     = (const int*)d_in[3];
    const int* left    = (const int*)d_in[4];

    float* img_out = (float*)d_out;
    float* msk_out = img_out + (size_t)B * C * OUT * OUT;

    dim3 block(OUT);
    dim3 grid(NBLK);
    hipLaunchKernelGGL(rrc_pair_kernel, grid, block, 0, stream,
                       image, mask, cs, top, left, img_out, msk_out);
}

// Round 11
// 34.034 us; speedup vs baseline: 1.0628x; 1.0262x over previous
//
#include <hip/hip_runtime.h>

// RandomResizedCropPair: bilinear crop-resize (image) + nearest crop-resize (mask)
// image: [32,3,512,512] f32, mask: [32,1,512,512] f32
// out: img [32,3,384,384] f32 ++ msk [32,1,384,384] f32
//
// R10: exact R7 structure, single A/B variable: nontemporal stores -> plain
// write-back stores. Hypothesis: NT forces the 74 MB store drain to HBM
// inside the timed dispatch; write-back lets stores complete at L2/L3 and
// drain after end-of-kernel. Everything else identical to R7 (33.0 us).

constexpr int OUT = 384;
constexpr int H = 512;
constexpr int W = 512;
constexpr int B = 32;
constexpr int C = 3;
constexpr int RPB = 4;                 // output rows per block
constexpr int GPB = OUT / RPB;         // 96 row-groups per image
constexpr int NBLK = B * GPB;          // 3072
constexpr int BPX  = NBLK / 8;         // 384 blocks/XCD = 4 whole images
constexpr int NSLOT = 6;               // input-row slots per channel
constexpr int LROWS = C * NSLOT;       // 18
constexpr int LDSW  = 520;             // dword row stride (512 data + guard + pad)

typedef float f32x4 __attribute__((ext_vector_type(4)));

__global__ __launch_bounds__(OUT) void rrc_pair_kernel(
    const float* __restrict__ image,
    const float* __restrict__ mask,
    const int* __restrict__ crop_size,
    const int* __restrict__ top,
    const int* __restrict__ left,
    float* __restrict__ img_out,
    float* __restrict__ msk_out)
{
    __shared__ float lds[LROWS * LDSW];

    // Bijective XCD swizzle: hw%8 = XCD, each XCD owns 4 whole images.
    const int hw = blockIdx.x;
    const int logical = (hw & 7) * BPX + (hw >> 3);
    const int b  = logical / GPB;                 // block-uniform
    const int i0 = (logical % GPB) * RPB;         // first output row
    const int tid = (int)threadIdx.x;             // = output column j

    const int cs = crop_size[b];
    const int t  = top[b];
    const int l  = left[b];
    const float csf = (float)cs;
    const float s   = csf / (float)OUT;           // match reference order

    // Block-uniform base input row (iy0 of the group's first output row).
    float cy0 = ((float)i0 + 0.5f) * s - 0.5f;
    cy0 = fminf(fmaxf(cy0, 0.0f), csf - 1.0f);
    const int base_y = (int)floorf(cy0);

    const float* imgb = image + (size_t)b * C * H * W;

    // --- stage 18 input rows (full 512 width) + guard word per row ---
    // 18*512 = 9216 floats = 2304 f32x4 chunks = 384 threads x 6.
    #pragma unroll
    for (int k = 0; k < 6; ++k) {
        const int q   = tid + k * OUT;            // chunk id 0..2303
        const int r   = q >> 7;                   // LDS row 0..17
        const int col = (q & 127) * 4;
        const int c    = r / NSLOT;
        const int slot = r % NSLOT;
        const int y = min(t + base_y + slot, H - 1);
        const float* src = imgb + ((size_t)c * H + (size_t)y) * W + col;
        f32x4 v = *(const f32x4*)src;
        *(f32x4*)&lds[r * LDSW + col] = v;
        if ((q & 127) == 127) lds[r * LDSW + 512] = v[3];  // guard = copy of col 511
    }

    // --- x geometry, once per thread ---
    float cx = ((float)tid + 0.5f) * s - 0.5f;
    cx = fminf(fmaxf(cx, 0.0f), csf - 1.0f);
    const int   ix0 = (int)floorf(cx);
    const float wx  = cx - (float)ix0;
    const int   x0  = ix0 + l;                    // read cols x0, x0+1 (guarded)

    const int mx = min((tid * cs) / OUT, cs - 1) + l;

    // --- mask gathers before the barrier (overlap staging latency) ---
    float mval[RPB];
    #pragma unroll
    for (int r4 = 0; r4 < RPB; ++r4) {
        const int i = i0 + r4;
        int my = min((i * cs) / OUT, cs - 1);
        mval[r4] = mask[((size_t)b * H + (size_t)(my + t)) * W + mx];
    }

    __syncthreads();

    #pragma unroll
    for (int r4 = 0; r4 < RPB; ++r4) {
        const int i = i0 + r4;
        float cy = ((float)i + 0.5f) * s - 0.5f;
        cy = fminf(fmaxf(cy, 0.0f), csf - 1.0f);
        int   iy0 = (int)floorf(cy);
        int   iy1 = min(iy0 + 1, cs - 1);
        float wy  = cy - (float)iy0;
        const int slot0 = iy0 - base_y;                       // 0..4
        const int slot1 = min(iy1 - base_y, NSLOT - 1);       // <= 5 (clamp = safety)

        const float w00 = (1.0f - wy) * (1.0f - wx);
        const float w01 = (1.0f - wy) * wx;
        const float w10 = wy * (1.0f - wx);
        const float w11 = wy * wx;

        const size_t o_base = (size_t)b * C * OUT * OUT + (size_t)i * OUT + (size_t)tid;

        #pragma unroll
        for (int c = 0; c < C; ++c) {
            const float* rA = &lds[(c * NSLOT + slot0) * LDSW + x0];
            const float* rB = &lds[(c * NSLOT + slot1) * LDSW + x0];
            float v00 = rA[0], v01 = rA[1];   // ds_read2_b32 pair
            float v10 = rB[0], v11 = rB[1];
            float rr = v00 * w00 + v01 * w01 + v10 * w10 + v11 * w11;
            img_out[o_base + (size_t)c * OUT * OUT] = rr;
        }
        msk_out[(size_t)b * OUT * OUT + (size_t)i * OUT + (size_t)tid] = mval[r4];
    }
}

extern "C" void kernel_launch(void* const* d_in, const int* in_sizes, int n_in,
                              void* d_out, int out_size, void* d_ws, size_t ws_size,
                              hipStream_t stream) {
    const float* image = (const float*)d_in[0];
    const float* mask  = (const float*)d_in[1];
    const int* cs      = (const int*)d_in[2];
    const int* top     = (const int*)d_in[3];
    const int* left    = (const int*)d_in[4];

    float* img_out = (float*)d_out;
    float* msk_out = img_out + (size_t)B * C * OUT * OUT;

    dim3 block(OUT);
    dim3 grid(NBLK);
    hipLaunchKernelGGL(rrc_pair_kernel, grid, block, 0, stream,
                       image, mask, cs, top, left, img_out, msk_out);
}

// Round 12
// 33.142 us; speedup vs baseline: 1.0914x; 1.0269x over previous
//
#include <hip/hip_runtime.h>

// RandomResizedCropPair: bilinear crop-resize (image) + nearest crop-resize (mask)
// image: [32,3,512,512] f32, mask: [32,1,512,512] f32
// out: img [32,3,384,384] f32 ++ msk [32,1,384,384] f32
//
// R11: R7 structure (4 rows/block, 18 staged rows, thread=column, NT stores,
// XCD swizzle) with staging switched to async global_load_lds(16B):
// no VGPR round-trip, no ds_writes; loads drain at the barrier's vmcnt.
// LDS rows are linear 512-dword (global_load_lds needs base+lane*16), with
// an 8-dword zeroed tail guard; the x0+1 edge overread is multiplied by
// exactly wx==0 so it contributes 0 (values are finite: staged data/zeros).

constexpr int OUT = 384;
constexpr int H = 512;
constexpr int W = 512;
constexpr int B = 32;
constexpr int C = 3;
constexpr int RPB = 4;                 // output rows per block
constexpr int GPB = OUT / RPB;         // 96 row-groups per image
constexpr int NBLK = B * GPB;          // 3072
constexpr int BPX  = NBLK / 8;         // 384 blocks/XCD = 4 whole images
constexpr int NSLOT = 6;               // input-row slots per channel
constexpr int LROWS = C * NSLOT;       // 18
constexpr int BUFSZ = LROWS * W;       // 9216 dwords, linear rows

typedef float f32x4 __attribute__((ext_vector_type(4)));

__global__ __launch_bounds__(OUT) void rrc_pair_kernel(
    const float* __restrict__ image,
    const float* __restrict__ mask,
    const int* __restrict__ crop_size,
    const int* __restrict__ top,
    const int* __restrict__ left,
    float* __restrict__ img_out,
    float* __restrict__ msk_out)
{
    __shared__ float lds[BUFSZ + 8];

    // Bijective XCD swizzle: hw%8 = XCD, each XCD owns 4 whole images.
    const int hw = blockIdx.x;
    const int logical = (hw & 7) * BPX + (hw >> 3);
    const int b  = logical / GPB;                 // block-uniform
    const int i0 = (logical % GPB) * RPB;         // first output row
    const int tid = (int)threadIdx.x;             // = output column j

    const int cs = crop_size[b];
    const int t  = top[b];
    const int l  = left[b];
    const float csf = (float)cs;
    const float s   = csf / (float)OUT;           // match reference order

    // Block-uniform base input row (iy0 of the group's first output row).
    float cy0 = ((float)i0 + 0.5f) * s - 0.5f;
    cy0 = fminf(fmaxf(cy0, 0.0f), csf - 1.0f);
    const int base_y = (int)floorf(cy0);

    const float* imgb = image + (size_t)b * C * H * W;

    // --- async stage 18 input rows (linear 512-dword rows) ---
    // chunk q = tid + k*384: LDS byte offset 16q = wave-uniform + lane*16. ✓
    #pragma unroll
    for (int k = 0; k < 6; ++k) {
        const int q   = tid + k * OUT;            // chunk id 0..2303
        const int r   = q >> 7;                   // LDS row 0..17
        const int col = (q & 127) * 4;
        const int c    = r / NSLOT;
        const int slot = r % NSLOT;
        const int y = min(t + base_y + slot, H - 1);
        const float* src = imgb + ((size_t)c * H + (size_t)y) * W + col;
        __builtin_amdgcn_global_load_lds(
            (const __attribute__((address_space(1))) void*)src,
            (__attribute__((address_space(3))) void*)&lds[q * 4],
            16, 0, 0);
    }
    if (tid < 8) lds[BUFSZ + tid] = 0.0f;         // zero tail guard

    // --- x geometry, once per thread ---
    float cx = ((float)tid + 0.5f) * s - 0.5f;
    cx = fminf(fmaxf(cx, 0.0f), csf - 1.0f);
    const int   ix0 = (int)floorf(cx);
    const float wx  = cx - (float)ix0;
    const int   x0  = ix0 + l;                    // read cols x0, x0+1 (guarded)

    const int mx = min((tid * cs) / OUT, cs - 1) + l;

    // --- mask gathers before the barrier (overlap staging latency) ---
    float mval[RPB];
    #pragma unroll
    for (int r4 = 0; r4 < RPB; ++r4) {
        const int i = i0 + r4;
        int my = min((i * cs) / OUT, cs - 1);
        mval[r4] = mask[((size_t)b * H + (size_t)(my + t)) * W + mx];
    }

    __syncthreads();   // drains vmcnt (global_load_lds) + lgkmcnt

    #pragma unroll
    for (int r4 = 0; r4 < RPB; ++r4) {
        const int i = i0 + r4;
        float cy = ((float)i + 0.5f) * s - 0.5f;
        cy = fminf(fmaxf(cy, 0.0f), csf - 1.0f);
        int   iy0 = (int)floorf(cy);
        int   iy1 = min(iy0 + 1, cs - 1);
        float wy  = cy - (float)iy0;
        const int slot0 = iy0 - base_y;                       // 0..4
        const int slot1 = min(iy1 - base_y, NSLOT - 1);       // <= 5

        const float w00 = (1.0f - wy) * (1.0f - wx);
        const float w01 = (1.0f - wy) * wx;
        const float w10 = wy * (1.0f - wx);
        const float w11 = wy * wx;

        const size_t o_base = (size_t)b * C * OUT * OUT + (size_t)i * OUT + (size_t)tid;

        #pragma unroll
        for (int c = 0; c < C; ++c) {
            const float* rA = &lds[(c * NSLOT + slot0) * W + x0];
            const float* rB = &lds[(c * NSLOT + slot1) * W + x0];
            float v00 = rA[0], v01 = rA[1];   // ds_read2_b32 pair
            float v10 = rB[0], v11 = rB[1];
            float rr = v00 * w00 + v01 * w01 + v10 * w10 + v11 * w11;
            __builtin_nontemporal_store(rr, img_out + o_base + (size_t)c * OUT * OUT);
        }
        __builtin_nontemporal_store(mval[r4],
            msk_out + (size_t)b * OUT * OUT + (size_t)i * OUT + (size_t)tid);
    }
}

extern "C" void kernel_launch(void* const* d_in, const int* in_sizes, int n_in,
                              void* d_out, int out_size, void* d_ws, size_t ws_size,
                              hipStream_t stream) {
    const float* image = (const float*)d_in[0];
    const float* mask  = (const float*)d_in[1];
    const int* cs      = (const int*)d_in[2];
    const int* top     = (const int*)d_in[3];
    const int* left    = (const int*)d_in[4];

    float* img_out = (float*)d_out;
    float* msk_out = img_out + (size_t)B * C * OUT * OUT;

    dim3 block(OUT);
    dim3 grid(NBLK);
    hipLaunchKernelGGL(rrc_pair_kernel, grid, block, 0, stream,
                       image, mask, cs, top, left, img_out, msk_out);
}

// Round 13
// 31.786 us; speedup vs baseline: 1.1380x; 1.0427x over previous
//
#include <hip/hip_runtime.h>

// RandomResizedCropPair: bilinear crop-resize (image) + nearest crop-resize (mask)
// image: [32,3,512,512] f32, mask: [32,1,512,512] f32
// out: img [32,3,384,384] f32 ++ msk [32,1,384,384] f32
//
// R12: shrink the sync domain. 128-thread blocks (2 waves), one block per
// (image, 4-row group, 128-column stripe). Each block stages an 18-row x
// 176-dword column window via global_load_lds (12.7 KB LDS -> 12 blocks/CU,
// 24 waves) instead of R7's full-width 6-wave blocks (4 blocks, big barrier
// convoy). Stripe window is clamped in-row globally; un-staged x0+1 taps
// happen only at wx==0 exactly (contribute 0; LDS tail guard zeroed).

constexpr int OUT = 384;
constexpr int H = 512;
constexpr int W = 512;
constexpr int B = 32;
constexpr int C = 3;
constexpr int RPB = 4;                  // output rows per group
constexpr int GPB = OUT / RPB;          // 96 groups per image
constexpr int SW  = 128;                // stripe width (output columns)
constexpr int NSTRIPE = OUT / SW;       // 3
constexpr int NSLOT = 6;                // input-row slots per channel
constexpr int LROWS = C * NSLOT;        // 18
constexpr int NW  = 176;                // LDS row width (dwords): 127*(511/384)+2 -> 171, pad
constexpr int NCH = NW / 4;             // 44 16B chunks per row
constexpr int TOT_CHUNK = LROWS * NCH;  // 792
constexpr int NBLK = B * GPB * NSTRIPE; // 9216
constexpr int BPX  = NBLK / 8;          // 1152 blocks/XCD = 4 whole images

typedef float f32x4 __attribute__((ext_vector_type(4)));

__global__ __launch_bounds__(128, 6) void rrc_pair_kernel(
    const float* __restrict__ image,
    const float* __restrict__ mask,
    const int* __restrict__ crop_size,
    const int* __restrict__ top,
    const int* __restrict__ left,
    float* __restrict__ img_out,
    float* __restrict__ msk_out)
{
    __shared__ float lds[LROWS * NW + 8];

    // Bijective XCD swizzle: hw%8 = XCD, each XCD owns 4 whole images.
    const int hw = blockIdx.x;
    const int logical = (hw & 7) * BPX + (hw >> 3);
    const int b   = logical / (GPB * NSTRIPE);
    const int rem = logical % (GPB * NSTRIPE);
    const int grp = rem / NSTRIPE;          // row group (stripes adjacent -> L2 row reuse)
    const int st  = rem % NSTRIPE;
    const int i0  = grp * RPB;
    const int c0  = st * SW;
    const int tid = (int)threadIdx.x;
    const int j   = c0 + tid;               // this thread's output column

    const int cs = crop_size[b];
    const int t  = top[b];
    const int l  = left[b];
    const float csf = (float)cs;
    const float s   = csf / (float)OUT;     // match reference: csf/SIZE first

    // Block-uniform base input row.
    float cy0 = ((float)i0 + 0.5f) * s - 0.5f;
    cy0 = fminf(fmaxf(cy0, 0.0f), csf - 1.0f);
    const int base_y = (int)floorf(cy0);

    // Block-uniform column window: [cbg, cbg+NW) absolute cols, in-row, 16B aligned.
    float cx0 = ((float)c0 + 0.5f) * s - 0.5f;
    cx0 = fminf(fmaxf(cx0, 0.0f), csf - 1.0f);
    const int gx0 = (int)floorf(cx0);
    const int cbg = min(l + gx0, W - NW) & ~3;

    const float* imgb = image + (size_t)b * C * H * W;

    // --- async stage: 18 rows x 44 chunks = 792 chunks; LDS byte addr = q*16 ---
    #pragma unroll
    for (int rd = 0; rd < 7; ++rd) {
        const int q = rd * 128 + tid;
        if (q < TOT_CHUNK) {
            const int r   = q / NCH;             // LDS row 0..17
            const int col = (q - r * NCH) * 4;   // dword col within window
            const int c    = r / NSLOT;
            const int slot = r - c * NSLOT;
            const int y = min(t + base_y + slot, H - 1);
            const float* src = imgb + ((size_t)(c * H + y)) * W + cbg + col;
            __builtin_amdgcn_global_load_lds(
                (const __attribute__((address_space(1))) void*)src,
                (__attribute__((address_space(3))) void*)&lds[q * 4],
                16, 0, 0);
        }
    }
    if (tid < 8) lds[LROWS * NW + tid] = 0.0f;   // zeroed tail guard

    // --- x geometry, once per thread ---
    float cx = ((float)j + 0.5f) * s - 0.5f;
    cx = fminf(fmaxf(cx, 0.0f), csf - 1.0f);
    const int   ix0 = (int)floorf(cx);
    const float wx  = cx - (float)ix0;
    const int   xoff = l + ix0 - cbg;            // in [0, NW-2]; +1 tap guarded

    const int mx = min((j * cs) / OUT, cs - 1) + l;

    // --- mask gathers before the barrier (overlap staging latency) ---
    float mval[RPB];
    #pragma unroll
    for (int r4 = 0; r4 < RPB; ++r4) {
        int my = min(((i0 + r4) * cs) / OUT, cs - 1);
        mval[r4] = mask[((size_t)b * H + (size_t)(my + t)) * W + mx];
    }

    __syncthreads();   // drains vmcnt (global_load_lds) for both waves

    #pragma unroll
    for (int r4 = 0; r4 < RPB; ++r4) {
        const int i = i0 + r4;
        float cy = ((float)i + 0.5f) * s - 0.5f;
        cy = fminf(fmaxf(cy, 0.0f), csf - 1.0f);
        int   iy0 = (int)floorf(cy);
        int   iy1 = min(iy0 + 1, cs - 1);
        float wy  = cy - (float)iy0;
        const int slot0 = iy0 - base_y;                  // 0..4
        const int slot1 = min(iy1 - base_y, NSLOT - 1);  // <=5 (safety)

        const float w00 = (1.0f - wy) * (1.0f - wx);
        const float w01 = (1.0f - wy) * wx;
        const float w10 = wy * (1.0f - wx);
        const float w11 = wy * wx;

        const size_t o_base = (size_t)b * C * OUT * OUT + (size_t)i * OUT + (size_t)j;

        #pragma unroll
        for (int c = 0; c < C; ++c) {
            const float* rA = &lds[(c * NSLOT + slot0) * NW + xoff];
            const float* rB = &lds[(c * NSLOT + slot1) * NW + xoff];
            float v00 = rA[0], v01 = rA[1];   // ds_read2_b32 pair
            float v10 = rB[0], v11 = rB[1];
            float rr = v00 * w00 + v01 * w01 + v10 * w10 + v11 * w11;
            __builtin_nontemporal_store(rr, img_out + o_base + (size_t)c * OUT * OUT);
        }
        __builtin_nontemporal_store(mval[r4],
            msk_out + (size_t)b * OUT * OUT + (size_t)i * OUT + (size_t)j);
    }
}

extern "C" void kernel_launch(void* const* d_in, const int* in_sizes, int n_in,
                              void* d_out, int out_size, void* d_ws, size_t ws_size,
                              hipStream_t stream) {
    const float* image = (const float*)d_in[0];
    const float* mask  = (const float*)d_in[1];
    const int* cs      = (const int*)d_in[2];
    const int* top     = (const int*)d_in[3];
    const int* left    = (const int*)d_in[4];

    float* img_out = (float*)d_out;
    float* msk_out = img_out + (size_t)B * C * OUT * OUT;

    dim3 block(128);
    dim3 grid(NBLK);
    hipLaunchKernelGGL(rrc_pair_kernel, grid, block, 0, stream,
                       image, mask, cs, top, left, img_out, msk_out);
}

// Round 14
// 31.761 us; speedup vs baseline: 1.1389x; 1.0008x over previous
//
#include <hip/hip_runtime.h>

// RandomResizedCropPair: bilinear crop-resize (image) + nearest crop-resize (mask)
// image: [32,3,512,512] f32, mask: [32,1,512,512] f32
// out: img [32,3,384,384] f32 ++ msk [32,1,384,384] f32
//
// R13: 2 rows x 128 cols per block (128 thr), each thread = 2 consecutive
// columns of one row -> f32x2 NT stores (4 store instrs/thread, was 16).
// Lane LDS-read stride ~2.13 dwords = 2-way bank overlap (free, m136) —
// avoids R8's stride-4 8-way conflict. NSLOT=4 staged slots per 2-row
// group -> 8.4 KB LDS -> 16 blocks/CU = 32 waves = 100% occupancy.
// global_load_lds staging, XCD swizzle, pre-barrier mask gathers kept.

constexpr int OUT = 384;
constexpr int H = 512;
constexpr int W = 512;
constexpr int B = 32;
constexpr int C = 3;
constexpr int RPB = 2;                  // output rows per block
constexpr int GPB = OUT / RPB;          // 192 row-groups per image
constexpr int SW  = 128;                // columns per block
constexpr int NSTRIPE = OUT / SW;       // 3
constexpr int NSLOT = 4;                // staged input-row slots per channel
constexpr int LROWS = C * NSLOT;        // 12
constexpr int NW  = 176;                // staged window width (dwords)
constexpr int NCH = NW / 4;             // 44 16B chunks per row
constexpr int TOT_CHUNK = LROWS * NCH;  // 528
constexpr int NBLK = B * GPB * NSTRIPE; // 18432
constexpr int BPX  = NBLK / 8;          // 2304 blocks/XCD = 4 whole images

typedef float f32x2 __attribute__((ext_vector_type(2)));

__global__ __launch_bounds__(128, 8) void rrc_pair_kernel(
    const float* __restrict__ image,
    const float* __restrict__ mask,
    const int* __restrict__ crop_size,
    const int* __restrict__ top,
    const int* __restrict__ left,
    float* __restrict__ img_out,
    float* __restrict__ msk_out)
{
    __shared__ float lds[LROWS * NW];

    // Bijective XCD swizzle: hw%8 = XCD, each XCD owns 4 whole images.
    const int hw = blockIdx.x;
    const int logical = (hw & 7) * BPX + (hw >> 3);
    const int b   = logical / (GPB * NSTRIPE);
    const int rem = logical % (GPB * NSTRIPE);
    const int grp = rem / NSTRIPE;
    const int st  = rem % NSTRIPE;
    const int i0  = grp * RPB;
    const int c0  = st * SW;
    const int tid = (int)threadIdx.x;

    const int cs = crop_size[b];
    const int t  = top[b];
    const int l  = left[b];
    const float csf = (float)cs;
    const float s   = csf / (float)OUT;     // match reference: csf/SIZE first

    // Block-uniform base input row (slots 0..3 cover both rows' taps).
    float cy0 = ((float)i0 + 0.5f) * s - 0.5f;
    cy0 = fminf(fmaxf(cy0, 0.0f), csf - 1.0f);
    const int base_y = (int)floorf(cy0);

    // Block-uniform column window [cbg, cbg+NW), in-row, 16B aligned.
    float cx0 = ((float)c0 + 0.5f) * s - 0.5f;
    cx0 = fminf(fmaxf(cx0, 0.0f), csf - 1.0f);
    const int gx0 = (int)floorf(cx0);
    const int cbg = min(l + gx0, W - NW) & ~3;

    const float* imgb = image + (size_t)b * C * H * W;

    // --- async stage: 12 rows x 44 chunks = 528; LDS byte addr = q*16 ---
    #pragma unroll
    for (int rd = 0; rd < 5; ++rd) {
        const int q = rd * 128 + tid;
        if (q < TOT_CHUNK) {
            const int r   = q / NCH;             // LDS row 0..11
            const int col = (q - r * NCH) * 4;   // dword col in window
            const int c    = r / NSLOT;
            const int slot = r - c * NSLOT;
            const int y = min(t + base_y + slot, H - 1);
            const float* src = imgb + ((size_t)(c * H + y)) * W + cbg + col;
            __builtin_amdgcn_global_load_lds(
                (const __attribute__((address_space(1))) void*)src,
                (__attribute__((address_space(3))) void*)&lds[q * 4],
                16, 0, 0);
        }
    }

    // --- this thread: row i0 + (tid>>6), columns j0, j0+1 ---
    const int lane = tid & 63;
    const int i  = i0 + (tid >> 6);
    const int j0 = c0 + 2 * lane;

    // x geometry for the 2 columns
    int   xo[2];
    float wxa[2];
    #pragma unroll
    for (int k = 0; k < 2; ++k) {
        float cx = ((float)(j0 + k) + 0.5f) * s - 0.5f;
        cx = fminf(fmaxf(cx, 0.0f), csf - 1.0f);
        int ix0 = (int)floorf(cx);
        wxa[k] = cx - (float)ix0;
        xo[k]  = l + ix0 - cbg;                  // in [0, NW-2]
    }

    // y geometry (one row per thread)
    float cy = ((float)i + 0.5f) * s - 0.5f;
    cy = fminf(fmaxf(cy, 0.0f), csf - 1.0f);
    int   iy0 = (int)floorf(cy);
    int   iy1 = min(iy0 + 1, cs - 1);
    float wy  = cy - (float)iy0;
    const int slot0 = iy0 - base_y;              // 0..2
    const int slot1 = min(iy1 - base_y, NSLOT - 1);

    // --- mask gathers before barrier (overlap staging latency) ---
    int my = min((i * cs) / OUT, cs - 1);
    const float* mrow = mask + ((size_t)b * H + (size_t)(my + t)) * W;
    f32x2 mv;
    #pragma unroll
    for (int k = 0; k < 2; ++k) {
        int mx = min(((j0 + k) * cs) / OUT, cs - 1);
        mv[k] = mrow[mx + l];
    }

    __syncthreads();   // drains vmcnt (global_load_lds)

    const float w00a[2] = { (1.0f - wy) * (1.0f - wxa[0]), (1.0f - wy) * (1.0f - wxa[1]) };
    const float w01a[2] = { (1.0f - wy) * wxa[0],          (1.0f - wy) * wxa[1] };
    const float w10a[2] = { wy * (1.0f - wxa[0]),          wy * (1.0f - wxa[1]) };
    const float w11a[2] = { wy * wxa[0],                   wy * wxa[1] };

    const size_t o_base = (size_t)b * C * OUT * OUT + (size_t)i * OUT + (size_t)j0;

    #pragma unroll
    for (int c = 0; c < C; ++c) {
        const float* rA = &lds[(c * NSLOT + slot0) * NW];
        const float* rB = &lds[(c * NSLOT + slot1) * NW];
        f32x2 o;
        #pragma unroll
        for (int k = 0; k < 2; ++k) {
            float v00 = rA[xo[k]], v01 = rA[xo[k] + 1];   // ds_read2_b32
            float v10 = rB[xo[k]], v11 = rB[xo[k] + 1];
            o[k] = v00 * w00a[k] + v01 * w01a[k] + v10 * w10a[k] + v11 * w11a[k];
        }
        __builtin_nontemporal_store(o, (f32x2*)(img_out + o_base + (size_t)c * OUT * OUT));
    }

    __builtin_nontemporal_store(mv,
        (f32x2*)(msk_out + (size_t)b * OUT * OUT + (size_t)i * OUT + (size_t)j0));
}

extern "C" void kernel_launch(void* const* d_in, const int* in_sizes, int n_in,
                              void* d_out, int out_size, void* d_ws, size_t ws_size,
                              hipStream_t stream) {
    const float* image = (const float*)d_in[0];
    const float* mask  = (const float*)d_in[1];
    const int* cs      = (const int*)d_in[2];
    const int* top     = (const int*)d_in[3];
    const int* left    = (const int*)d_in[4];

    float* img_out = (float*)d_out;
    float* msk_out = img_out + (size_t)B * C * OUT * OUT;

    dim3 block(128);
    dim3 grid(NBLK);
    hipLaunchKernelGGL(rrc_pair_kernel, grid, block, 0, stream,
                       image, mask, cs, top, left, img_out, msk_out);
}